// Round 1
// baseline (154.699 us; speedup 1.0000x reference)
//
#include <hip/hip_runtime.h>

// DPQ network: response argmax (f32) + codebook-gather GEMM (bf16 MFMA)
// B=32768, C=32, K=256, D_SUB=16, D_IN=512, D_OUT=512

#define NB 32768
#define NC 32
#define NK 256
#define NDS 16
#define NDIN 512
#define NDOUT 512

typedef __attribute__((ext_vector_type(8))) short s8v;   // 8 bf16 in 4 VGPRs
typedef __attribute__((ext_vector_type(4))) float f4v;   // MFMA accumulator

__device__ __forceinline__ unsigned short f2bf(float f) {
  unsigned int u = __float_as_uint(f);
  u += 0x7fffu + ((u >> 16) & 1u);   // RNE
  return (unsigned short)(u >> 16);
}

__device__ __forceinline__ void gload16(const void* g, void* l) {
  __builtin_amdgcn_global_load_lds(
      (const __attribute__((address_space(1))) void*)g,
      (__attribute__((address_space(3))) void*)l, 16, 0, 0);
}

// ---------------------------------------------------------------------------
// Kernel 0: Wt[n][k] = bf16(W[k][n])  (transposed for B-operand staging), and
//           centsB = bf16(centroids)  (gather source for GEMM A-operand)
// ---------------------------------------------------------------------------
__global__ __launch_bounds__(256) void k_prep(const float* __restrict__ W,
                                              const float* __restrict__ cents,
                                              unsigned short* __restrict__ Wt,
                                              unsigned short* __restrict__ centsB) {
  const int t = threadIdx.x;
  const int bid = blockIdx.x;
  if (bid < 256) {
    // 32x32 tile transpose of W (512x512)
    __shared__ float tile[32][33];
    const int k0 = (bid >> 4) << 5;
    const int n0 = (bid & 15) << 5;
    const int tx = t & 31, ty = t >> 5;  // 32 x 8
#pragma unroll
    for (int i = 0; i < 4; ++i) {
      int r = ty + i * 8;
      tile[r][tx] = W[(size_t)(k0 + r) * NDOUT + n0 + tx];
    }
    __syncthreads();
#pragma unroll
    for (int i = 0; i < 4; ++i) {
      int r = ty + i * 8;
      Wt[(size_t)(n0 + r) * NDIN + k0 + tx] = f2bf(tile[tx][r]);
    }
  } else {
    // cast centroids: 131072 floats, blocks 256..287, 16 per thread
    const int i0 = (bid - 256) * 4096 + t * 16;
#pragma unroll
    for (int j = 0; j < 4; ++j) {
      float4 v = *(const float4*)(cents + i0 + j * 4);
      unsigned short h0 = f2bf(v.x), h1 = f2bf(v.y), h2 = f2bf(v.z), h3 = f2bf(v.w);
      ushort4 h = make_ushort4(h0, h1, h2, h3);
      *(ushort4*)(centsB + i0 + j * 4) = h;
    }
  }
}

// ---------------------------------------------------------------------------
// Kernel 1: per (b,c): response = <inputs[b,c,:], centroids[c,k,:]>, max/argmax
// block = 1024 b-values x 1 c; 4 b per thread; centroids[c] in LDS (16 KiB)
// ---------------------------------------------------------------------------
__global__ __launch_bounds__(256) void k_phase1(const float* __restrict__ inputs,
                                                const float* __restrict__ cents,
                                                float* __restrict__ negout,
                                                float* __restrict__ codefout,
                                                int* __restrict__ codeint) {
  __shared__ float4 lc[NK * 4];  // 256 k x 16 floats = 16 KiB
  const int t = threadIdx.x;
  const int c = blockIdx.y;
  {
    const float4* cg = (const float4*)(cents + (size_t)c * NK * NDS);
#pragma unroll
    for (int i = 0; i < 4; ++i) lc[t + i * 256] = cg[t + i * 256];
  }
  __syncthreads();

  const int b0 = blockIdx.x * 1024 + t;
  float in[4][16];
#pragma unroll
  for (int i = 0; i < 4; ++i) {
    const float4* ip = (const float4*)(inputs + ((size_t)(b0 + i * 256) * NC + c) * NDS);
#pragma unroll
    for (int j = 0; j < 4; ++j) {
      float4 v = ip[j];
      in[i][j * 4 + 0] = v.x; in[i][j * 4 + 1] = v.y;
      in[i][j * 4 + 2] = v.z; in[i][j * 4 + 3] = v.w;
    }
  }

  float best[4];
  int bk[4];
#pragma unroll
  for (int i = 0; i < 4; ++i) { best[i] = -3.0e38f; bk[i] = 0; }

#pragma unroll 2
  for (int k = 0; k < NK; ++k) {
    float cv[16];
    float4 q0 = lc[k * 4 + 0]; cv[0] = q0.x; cv[1] = q0.y; cv[2] = q0.z; cv[3] = q0.w;
    float4 q1 = lc[k * 4 + 1]; cv[4] = q1.x; cv[5] = q1.y; cv[6] = q1.z; cv[7] = q1.w;
    float4 q2 = lc[k * 4 + 2]; cv[8] = q2.x; cv[9] = q2.y; cv[10] = q2.z; cv[11] = q2.w;
    float4 q3 = lc[k * 4 + 3]; cv[12] = q3.x; cv[13] = q3.y; cv[14] = q3.z; cv[15] = q3.w;
#pragma unroll
    for (int i = 0; i < 4; ++i) {
      float s0 = in[i][0] * cv[0];
      float s1 = in[i][1] * cv[1];
#pragma unroll
      for (int d = 2; d < 16; d += 2) {
        s0 = fmaf(in[i][d], cv[d], s0);
        s1 = fmaf(in[i][d + 1], cv[d + 1], s1);
      }
      float dot = s0 + s1;
      if (dot > best[i]) { best[i] = dot; bk[i] = k; }  // strict > => first-index tie
    }
  }

#pragma unroll
  for (int i = 0; i < 4; ++i) {
    size_t o = (size_t)(b0 + i * 256) * NC + c;
    negout[o] = -best[i];
    codefout[o] = (float)bk[i];
    codeint[o] = bk[i];
  }
}

// ---------------------------------------------------------------------------
// Kernel 2: product = gather(centsB, codes) @ W   via bf16 MFMA
// 128x128 tile, BK=64, 4 waves (2x2 of 64x64), A gathered via global_load_lds
// ---------------------------------------------------------------------------
__global__ __launch_bounds__(256) void k_gemm(const unsigned short* __restrict__ centsB,
                                              const int* __restrict__ codeint,
                                              const unsigned short* __restrict__ Wt,
                                              float* __restrict__ out) {
  __shared__ __align__(16) unsigned short As[128 * 64];  // 16 KiB (XOR-swizzled)
  __shared__ __align__(16) unsigned short Bs[128 * 64];  // 16 KiB (XOR-swizzled)
  __shared__ int lcode[128 * 33];                        // codes, padded vs bank conflict

  const int t = threadIdx.x;
  const int l = t & 63;
  const int w = t >> 6;
  const int wm = w >> 1, wn = w & 1;
  const int m0 = blockIdx.x * 128;
  const int n0 = blockIdx.y * 128;

  // preload this block's codes: rows m0..m0+127, all 32 c (coalesced int4)
  {
    const int4* cp = (const int4*)(codeint + (size_t)m0 * NC);
#pragma unroll
    for (int i = 0; i < 4; ++i) {
      int idx = t + i * 256;          // int4 index; row = idx/8, col = (idx%8)*4
      int4 v = cp[idx];
      int row = idx >> 3, col = (idx & 7) * 4;
      lcode[row * 33 + col + 0] = v.x;
      lcode[row * 33 + col + 1] = v.y;
      lcode[row * 33 + col + 2] = v.z;
      lcode[row * 33 + col + 3] = v.w;
    }
  }

  f4v acc[4][4] = {};
  const int s = t & 7;        // 16B slot within a 128B row
  const int rq = t >> 3;      // 0..31: row within a 32-row staging chunk

  for (int kt = 0; kt < 8; ++kt) {
    __syncthreads();  // iter0: lcode visible; later: all frag reads of As/Bs done
    const int c0 = kt * 4;
    // ---- stage A (gathered): As[row][slot] = A[m0+row][kt*64 + (slot^(row&7))*8 ..]
#pragma unroll
    for (int i = 0; i < 4; ++i) {
      int lr = i * 32 + rq;
      int srcslot = s ^ (lr & 7);
      int cl = srcslot >> 1, half = srcslot & 1;
      int code = lcode[lr * 33 + c0 + cl];
      const unsigned short* gsrc =
          centsB + ((size_t)((c0 + cl) * NK + code) * NDS + half * 8);
      gload16(gsrc, (char*)As + i * 4096 + (w << 10));
    }
    // ---- stage B: Bs[n][slot] = Wt[n0+n][kt*64 + (slot^(n&7))*8 ..]
#pragma unroll
    for (int i = 0; i < 4; ++i) {
      int lr = i * 32 + rq;
      int k16 = s ^ (lr & 7);
      const unsigned short* gsrc = Wt + (size_t)(n0 + lr) * NDIN + kt * 64 + k16 * 8;
      gload16(gsrc, (char*)Bs + i * 4096 + (w << 10));
    }
    __syncthreads();  // compiler inserts vmcnt(0) drain: LDS tiles ready

    s8v af[4][2], bfr[4][2];
#pragma unroll
    for (int mf = 0; mf < 4; ++mf)
#pragma unroll
      for (int ks = 0; ks < 2; ++ks) {
        int row = wm * 64 + mf * 16 + (l & 15);
        int slot = ks * 4 + (l >> 4);
        af[mf][ks] = *(const s8v*)((const char*)As + row * 128 + ((slot ^ (row & 7)) << 4));
      }
#pragma unroll
    for (int nf = 0; nf < 4; ++nf)
#pragma unroll
      for (int ks = 0; ks < 2; ++ks) {
        int row = wn * 64 + nf * 16 + (l & 15);
        int slot = ks * 4 + (l >> 4);
        bfr[nf][ks] = *(const s8v*)((const char*)Bs + row * 128 + ((slot ^ (row & 7)) << 4));
      }
#pragma unroll
    for (int ks = 0; ks < 2; ++ks)
#pragma unroll
      for (int mf = 0; mf < 4; ++mf)
#pragma unroll
        for (int nf = 0; nf < 4; ++nf)
          acc[mf][nf] = __builtin_amdgcn_mfma_f32_16x16x32_bf16(
              af[mf][ks], bfr[nf][ks], acc[mf][nf], 0, 0, 0);
  }

  // epilogue: C[row][col], row=(l>>4)*4+r, col=l&15 within each 16x16 frag
#pragma unroll
  for (int mf = 0; mf < 4; ++mf)
#pragma unroll
    for (int nf = 0; nf < 4; ++nf)
#pragma unroll
      for (int r = 0; r < 4; ++r) {
        int row = m0 + wm * 64 + mf * 16 + (l >> 4) * 4 + r;
        int col = n0 + wn * 64 + nf * 16 + (l & 15);
        out[(size_t)row * NDOUT + col] = acc[mf][nf][r];
      }
}

// ---------------------------------------------------------------------------
extern "C" void kernel_launch(void* const* d_in, const int* in_sizes, int n_in,
                              void* d_out, int out_size, void* d_ws, size_t ws_size,
                              hipStream_t stream) {
  const float* inputs = (const float*)d_in[0];   // (B, C, 16) f32
  const float* cents  = (const float*)d_in[1];   // (C, K, 16) f32
  const float* W      = (const float*)d_in[2];   // (512, 512) f32

  float* out = (float*)d_out;
  float* negout   = out + (size_t)NB * NDOUT;            // (B, C)
  float* codefout = negout + (size_t)NB * NC;            // (B, C) as float values

  unsigned short* Wt     = (unsigned short*)d_ws;                          // 512 KiB
  unsigned short* centsB = (unsigned short*)((char*)d_ws + 512 * 1024);    // 256 KiB
  int* codeint           = (int*)((char*)d_ws + (1 << 20));                // 4 MiB

  k_prep<<<288, 256, 0, stream>>>(W, cents, Wt, centsB);
  k_phase1<<<dim3(NB / 1024, NC), 256, 0, stream>>>(inputs, cents, negout, codefout, codeint);
  k_gemm<<<dim3(NB / 128, NDOUT / 128), 256, 0, stream>>>(centsB, codeint, Wt, out);
}